// Round 18
// baseline (38.101 us; speedup 1.0000x reference)
//
#include <hip/hip_runtime.h>

typedef __bf16 bf16x8 __attribute__((ext_vector_type(8)));
typedef float f32x16 __attribute__((ext_vector_type(16)));
typedef unsigned u32x2 __attribute__((ext_vector_type(2)));

#define BB 2
#define HH 56
#define WW 56
#define NN 2
#define CC 128
#define NH 8
#define DD 16
#define WSP 7
#define LQ 784           // tokens per window = 56*7*2
#define KB_TOK 800       // K rows (zero-padded 784..799)
#define VT_STRIDE 808    // V^T token stride (bf16 elems)
#define NKC 25           // K chunks of 32
#define NINST 128        // 16 windows * 8 heads
#define BPI 5            // blocks per instance
#define NWAVE 5          // waves per block (1 Q-tile each)

// LDS layout (bytes): K [800][16] bf16 (swizzled 16B units) | V^T [16][808]
// bf16 | w [9][16] f32 | ones
#define K_OFF 0
#define V_OFF 25600
#define W_OFF 51456
#define ONES_OFF 52032
#define SMEM_BYTES 52064

// scale * log2(e) so P = exp2(S) directly (no max-tracking; S bounded)
#define QSCALE 0.3606737602222409f

union U2 { __bf16 h[2]; unsigned u; };
union U4 { unsigned u[4]; bf16x8 v; };
union H8 { bf16x8 v; uint4 q; };

static __device__ __forceinline__ float4 f4zero() { float4 r; r.x = r.y = r.z = r.w = 0.f; return r; }
static __device__ __forceinline__ float4 f4add(float4 a, float4 b) {
    float4 r; r.x = a.x + b.x; r.y = a.y + b.y; r.z = a.z + b.z; r.w = a.w + b.w; return r;
}
static __device__ __forceinline__ float4 f4fma(float4 acc, float4 w, float4 s) {
    acc.x += w.x * s.x; acc.y += w.y * s.y; acc.z += w.z * s.z; acc.w += w.w * s.w; return acc;
}

// R14 base with a cold-latency-optimized front end: Q + ALL pack loads are
// issued in one up-front burst (max MLP on the cold pass), then converted and
// written to LDS. Grid 640 = 128 inst * 5 parts, XCD-affine.
__global__ __launch_bounds__(320) void attn_fused(const float* __restrict__ q_g,
                                                  const float* __restrict__ k_g,
                                                  const float* __restrict__ v_g,
                                                  const float* __restrict__ conv_w,
                                                  float* __restrict__ out) {
    __shared__ alignas(16) char smem[SMEM_BYTES];
    uint4*  K16   = (uint4*)(smem + K_OFF);      // 16B units, swizzled
    __bf16* Vlds  = (__bf16*)(smem + V_OFF);
    float*  wlds  = (float*)(smem + W_OFF);
    __bf16* onesb = (__bf16*)(smem + ONES_OFF);

    const int bid  = blockIdx.x;
    const int g    = bid >> 3;             // 0..79
    const int inst = (bid & 7) + 8 * (g / BPI);
    const int part = g % BPI;
    const int head = inst & 7;
    const int win  = inst >> 3;
    const int b    = win >> 3, wj = win & 7;
    const int tid  = threadIdx.x;

    // ---- per-lane geometry (needed for early Q load) ----
    const int w    = tid >> 6;             // 0..4
    const int lane = tid & 63;
    const int col  = lane & 31;            // query col / key row / V^T row
    const int h    = lane >> 5;
    const int qt   = part * NWAVE + w;     // 0..24
    const int myq  = qt * 32 + col;
    const int sib  = myq ^ 1;

    const int myqc = myq < LQ ? myq : LQ - 1;
    const int pos = myqc >> 1, n = myqc & 1;
    const int y = pos / WSP, xl = pos - y * WSP;
    const long ooff = ((long)(((b * HH + y) * WW + wj * WSP + xl) * NN + n)) * CC + head * DD;

    // ---- issue Q load early (cold miss overlaps the pack burst) ----
    float4 q0 = *(const float4*)(q_g + ooff + 8 * h);
    float4 q1 = *(const float4*)(q_g + ooff + 8 * h + 4);

    // ---- stage conv weights transposed [k][16] + ones buffer ----
    if (tid < 144) {
        int c = tid & 15, k = tid >> 4;
        wlds[k * 16 + c] = conv_w[(head * 16 + c) * 9 + k];
    } else if (tid < 160) {
        onesb[tid - 144] = (__bf16)1.f;
    }

    // ---- pack phase, MLP-maximized: issue ALL loads, then convert+write ----
    // tokens: t0 = tid (always <800), t1 = tid+320 (<800), t2 = tid+640 (if <800)
    {
        const int t0 = tid, t1 = tid + 320, t2 = tid + 640;
        const bool v2 = t2 < KB_TOK;

        auto tok_off = [&](int tok) -> long {
            int tc = tok < LQ ? tok : LQ - 1;
            int tpos = tc >> 1, tn = tc & 1;
            int ty = tpos / WSP, txl = tpos - ty * WSP;
            return ((long)(((b * HH + ty) * WW + wj * WSP + txl) * NN + tn)) * CC + head * DD;
        };
        const long o0 = tok_off(t0), o1 = tok_off(t1), o2 = v2 ? tok_off(t2) : o0;

        // burst: 16-24 independent global loads
        float4 k00 = *(const float4*)(k_g + o0),      k01 = *(const float4*)(k_g + o0 + 4);
        float4 k02 = *(const float4*)(k_g + o0 + 8),  k03 = *(const float4*)(k_g + o0 + 12);
        float4 v00 = *(const float4*)(v_g + o0),      v01 = *(const float4*)(v_g + o0 + 4);
        float4 v02 = *(const float4*)(v_g + o0 + 8),  v03 = *(const float4*)(v_g + o0 + 12);
        float4 k10 = *(const float4*)(k_g + o1),      k11 = *(const float4*)(k_g + o1 + 4);
        float4 k12 = *(const float4*)(k_g + o1 + 8),  k13 = *(const float4*)(k_g + o1 + 12);
        float4 v10 = *(const float4*)(v_g + o1),      v11 = *(const float4*)(v_g + o1 + 4);
        float4 v12 = *(const float4*)(v_g + o1 + 8),  v13 = *(const float4*)(v_g + o1 + 12);
        float4 k20 = *(const float4*)(k_g + o2),      k21 = *(const float4*)(k_g + o2 + 4);
        float4 k22 = *(const float4*)(k_g + o2 + 8),  k23 = *(const float4*)(k_g + o2 + 12);
        float4 v20 = *(const float4*)(v_g + o2),      v21 = *(const float4*)(v_g + o2 + 4);
        float4 v22 = *(const float4*)(v_g + o2 + 8),  v23 = *(const float4*)(v_g + o2 + 12);

        auto wr = [&](int tok, bool valid, float4 ka, float4 kb, float4 kc, float4 kd,
                      float4 va, float4 vb, float4 vc, float4 vd) {
            float kv[16], vv[16];
            *(float4*)&kv[0] = ka; *(float4*)&kv[4] = kb;
            *(float4*)&kv[8] = kc; *(float4*)&kv[12] = kd;
            *(float4*)&vv[0] = va; *(float4*)&vv[4] = vb;
            *(float4*)&vv[8] = vc; *(float4*)&vv[12] = vd;
            const bool live = valid && tok < LQ;
            H8 lo, hi;
#pragma unroll
            for (int i = 0; i < 8; ++i) {
                lo.v[i] = live ? (__bf16)kv[i]     : (__bf16)0.f;
                hi.v[i] = live ? (__bf16)kv[8 + i] : (__bf16)0.f;
            }
            if (valid) {
                int sw = tok & 7;
                K16[(tok * 2)     ^ sw] = lo.q;
                K16[(tok * 2 + 1) ^ sw] = hi.q;
#pragma unroll
                for (int d = 0; d < 16; ++d)
                    Vlds[d * VT_STRIDE + tok] = live ? (__bf16)vv[d] : (__bf16)0.f;
            }
        };
        wr(t0, true, k00, k01, k02, k03, v00, v01, v02, v03);
        wr(t1, true, k10, k11, k12, k13, v10, v11, v12, v13);
        wr(t2, v2,   k20, k21, k22, k23, v20, v21, v22, v23);
    }
    __syncthreads();

    // ---- Q fragment (B operand): col=query, k = d = 8h..8h+7 ----
    bf16x8 qfv;
    {
        H8 qq;
        qq.v[0] = (__bf16)(q0.x * QSCALE); qq.v[1] = (__bf16)(q0.y * QSCALE);
        qq.v[2] = (__bf16)(q0.z * QSCALE); qq.v[3] = (__bf16)(q0.w * QSCALE);
        qq.v[4] = (__bf16)(q1.x * QSCALE); qq.v[5] = (__bf16)(q1.y * QSCALE);
        qq.v[6] = (__bf16)(q1.z * QSCALE); qq.v[7] = (__bf16)(q1.w * QSCALE);
        qfv = qq.v;
    }

    f32x16 acc, zv;
#pragma unroll
    for (int i = 0; i < 16; ++i) { acc[i] = 0.f; zv[i] = 0.f; }

    const uint4* kbase = K16 + ((col * 2 + h) ^ (col & 7));   // + c*64
    const char* vbase;
    int vstep, tstep;
    if (col < 16) {
        vbase = (const char*)Vlds + col * (VT_STRIDE * 2) + h * 16;
        vstep = 64; tstep = 32;
    } else {
        vbase = (const char*)onesb;        // stride-0 ones broadcast (lsum)
        vstep = 0; tstep = 0;
    }

    for (int c = 0; c < NKC; ++c) {
        U4 kf;
        *(uint4*)&kf = kbase[c * 64];
        f32x16 st = __builtin_amdgcn_mfma_f32_32x32x16_bf16(kf.v, qfv, zv, 0, 0, 0);

        float p[16];
        if (c == qt || c == NKC - 1) {
#pragma unroll
            for (int r = 0; r < 16; ++r) {
                int kr = (r & 3) + 8 * (r >> 2) + 4 * h;
                int gk = c * 32 + kr;
                p[r] = (gk >= LQ || gk == sib) ? 0.f : __builtin_amdgcn_exp2f(st[r]);
            }
        } else {
#pragma unroll
            for (int r = 0; r < 16; ++r) p[r] = __builtin_amdgcn_exp2f(st[r]);
        }

        unsigned pk[4][2];
#pragma unroll
        for (int b2 = 0; b2 < 4; ++b2) {
            U2 a, bb;
            a.h[0]  = (__bf16)p[4 * b2 + 0];
            a.h[1]  = (__bf16)p[4 * b2 + 1];
            bb.h[0] = (__bf16)p[4 * b2 + 2];
            bb.h[1] = (__bf16)p[4 * b2 + 3];
            pk[b2][0] = a.u;
            pk[b2][1] = bb.u;
        }

#pragma unroll
        for (int t = 0; t < 2; ++t) {
            U4 pb;
#pragma unroll
            for (int j = 0; j < 2; ++j) {
#if __has_builtin(__builtin_amdgcn_permlane32_swap)
                u32x2 rr = __builtin_amdgcn_permlane32_swap(pk[2 * t][j], pk[2 * t + 1][j], false, false);
                pb.u[j]     = rr[0];
                pb.u[2 + j] = rr[1];
#else
                unsigned swa = __shfl_xor(pk[2 * t][j], 32, 64);
                unsigned swb = __shfl_xor(pk[2 * t + 1][j], 32, 64);
                pb.u[j]     = h ? swb : pk[2 * t][j];
                pb.u[2 + j] = h ? pk[2 * t + 1][j] : swa;
#endif
            }
            bf16x8 vf = *(const bf16x8*)(vbase + c * vstep + t * tstep);
            acc = __builtin_amdgcn_mfma_f32_32x32x16_bf16(vf, pb.v, acc, 0, 0, 0);
        }
    }

    // ---- epilogue: in-register depthwise-conv RPE + store (no RMW) ----
    // acc[8] = lsum (ones row); regs 0..3 -> d=4h+r, 4..7 -> d=8+4h+(r-4)
    if (myq < LQ) {
        float inv = 1.f / acc[8];

        const int xg = wj * WSP + xl;
        const long rowbase = ((long)(b * HH + y) * WW + xg) * (NN * CC) + head * DD;

        float4 cv0 = f4zero(), cv1 = f4zero();
        float4 sc0 = f4zero(), sc1 = f4zero();
        float4 vn0 = f4zero(), vn1 = f4zero();

#pragma unroll
        for (int dy = -1; dy <= 1; ++dy) {
            int yy = y + dy;
#pragma unroll
            for (int dx = -1; dx <= 1; ++dx) {
                int xx = xg + dx;
                if (yy < 0 || yy >= HH || xx < 0 || xx >= WW) continue;
                int k = (dy + 1) * 3 + (dx + 1);
                const float* p = v_g + rowbase + ((long)dy * WW + dx) * (NN * CC);
                float4 a0 = *(const float4*)(p + 4 * h);
                float4 b0 = *(const float4*)(p + CC + 4 * h);
                float4 a1 = *(const float4*)(p + 8 + 4 * h);
                float4 b1 = *(const float4*)(p + CC + 8 + 4 * h);
                float4 w0 = *(const float4*)(wlds + k * 16 + 4 * h);
                float4 w1 = *(const float4*)(wlds + k * 16 + 8 + 4 * h);
                float4 S0 = f4add(a0, b0);
                float4 S1 = f4add(a1, b1);
                cv0 = f4fma(cv0, w0, S0);
                cv1 = f4fma(cv1, w1, S1);
                if (dy == 0 && dx == 0) {
                    sc0 = S0; sc1 = S1;
                    vn0 = n ? b0 : a0;
                    vn1 = n ? b1 : a1;
                }
            }
        }
        float4 wc0 = *(const float4*)(wlds + 4 * 16 + 4 * h);
        float4 wc1 = *(const float4*)(wlds + 4 * 16 + 8 + 4 * h);

        float* po = out + ooff;
        float4 r0, r1;
        r0.x = cv0.x + wc0.x * (vn0.x - sc0.x) + acc[0] * inv;
        r0.y = cv0.y + wc0.y * (vn0.y - sc0.y) + acc[1] * inv;
        r0.z = cv0.z + wc0.z * (vn0.z - sc0.z) + acc[2] * inv;
        r0.w = cv0.w + wc0.w * (vn0.w - sc0.w) + acc[3] * inv;
        r1.x = cv1.x + wc1.x * (vn1.x - sc1.x) + acc[4] * inv;
        r1.y = cv1.y + wc1.y * (vn1.y - sc1.y) + acc[5] * inv;
        r1.z = cv1.z + wc1.z * (vn1.z - sc1.z) + acc[6] * inv;
        r1.w = cv1.w + wc1.w * (vn1.w - sc1.w) + acc[7] * inv;
        *(float4*)(po + 4 * h) = r0;
        *(float4*)(po + 8 + 4 * h) = r1;
    }
}

extern "C" void kernel_launch(void* const* d_in, const int* in_sizes, int n_in,
                              void* d_out, int out_size, void* d_ws, size_t ws_size,
                              hipStream_t stream) {
    const float* q = (const float*)d_in[0];
    const float* k = (const float*)d_in[1];
    const float* v = (const float*)d_in[2];
    const float* w = (const float*)d_in[3];
    float* out = (float*)d_out;

    attn_fused<<<NINST * BPI, 320, 0, stream>>>(q, k, v, w, out);
}